// Round 12
// baseline (91.592 us; speedup 1.0000x reference)
//
#include <hip/hip_runtime.h>

// KDE joint histogram = dense split-K INT8 MFMA GEMM, sparse scatter staging,
// ping-pong K-tiles (1 barrier/step), 128x256 block tile (512 thr, 8 waves).
// joint[b,i,j] = sum_k kx[b,k,i]*ky[b,k,j]; quantize q = round(127*kernel)
// (i8 zeroes below 1/254 -> ±3.33-bin support, window = 7 bins). 127^2 scale
// cancels in normalization; i32 accumulation exact. Each block-step stages 64
// particles (2 axes) but feeds a 2x-wide output tile vs the 128x128 version:
// scatter DS ops / exp2 / barriers HALVE per output. Consume & MFMA invariant.
// NOTE: harness d_ws 0xAA poison (268 MB fill, ~46 us) sits inside the timed
// window every round — immovable floor; controllable part is gemm+tail only.

#define B_     4
#define N_     50000
#define M_     256
#define BK     64
#define NCH    64               // grid 2*64*4 = 512 blocks = 2 blocks/CU exact
#define KSTEPS 13               // 13*64 = 832/chunk; 64*832 = 53248 >= N
#define KCH    (KSTEPS * BK)
#define LDKB   80               // tile row stride in BYTES (16B-aligned)
#define AROWS  128              // A (kx) tile rows
#define BROWS  256              // B (ky) tile rows (full j extent)
#define AXA    ((AROWS + 1) * LDKB)   // 10320 B (incl. dump row)
#define AXBB   ((BROWS + 1) * LDKB)   // 20560 B (incl. dump row)
#define BUFB   (AXA + AXBB)           // 30880 B per ping-pong buffer
#define BLOCK  512
#define WINB   7                // bins per window (covers ±3.5)
#define CS2    0.72134752f      // 0.5*log2(e): exp(-0.5 d^2) = 2^(-CS2*d^2)
#define HINV   0.36787944f      // 2^(-2*CS2) = 1/e

#if __has_builtin(__builtin_amdgcn_exp2f)
  #define EXP2(t) __builtin_amdgcn_exp2f(t)
#else
  #define EXP2(t) exp2f(t)
#endif

typedef __attribute__((ext_vector_type(4))) int i32x4;

__device__ __forceinline__ unsigned short bf16ru(float f) {  // round-half-up
    return (unsigned short)((__builtin_bit_cast(unsigned, f) + 0x8000u) >> 16);
}
__device__ __forceinline__ float bf2f(unsigned short u) {
    return __builtin_bit_cast(float, ((unsigned)u) << 16);
}

__global__ __launch_bounds__(BLOCK, 4) void kde_gemm(
    const float* __restrict__ xs, const float* __restrict__ ys,
    const float* __restrict__ bins, unsigned short* __restrict__ partial,
    float* __restrict__ ws2, int wide)
{
    __shared__ __align__(16) char tiles[2 * BUFB];   // 61760 B
    __shared__ float sred[8];

    const int tid   = threadIdx.x;
    const int itile = blockIdx.x;            // 0,1 -> output rows [itile*128,+128)
    const int chunk = blockIdx.y;            // 0..NCH-1
    const int b     = blockIdx.z;

    const int ilo = itile * 128;
    const float bin0  = bins[0];
    const float invbw = 1.0f / (bins[1] - bin0);

    // ---- bulk-zero both buffers (incl. dump rows) ----
    {
        int4* za = (int4*)tiles;
        const int4 z4 = {0, 0, 0, 0};
        for (int t = tid; t < (2 * BUFB) / 16; t += BLOCK) za[t] = z4;
    }

    const int w    = tid >> 6;
    const int lane = tid & 63;
    const int lm   = lane & 15;
    const int quad = lane >> 4;

    // ---- scatter role: wave 0 -> x/A (128 rows), wave 1 -> y/B (256 rows) ----
    const bool sc      = (w < 2);
    const int  rowlo   = (w == 0) ? ilo : 0;
    const unsigned clip = (w == 0) ? 128u : 256u;
    const int  cb0     = ((w == 0) ? 0 : AXA) + lane;  // column base in buffer
    const float* coord = ((w == 0) ? xs : ys) + b * N_;
    const int  k0      = chunk * KCH;
    char* const tb     = tiles;

    // ---- consume role: 8 waves in 2 row-groups x 4 col-blocks, 64x64 each ----
    const int R0 = (w >> 2) * 64;
    const int wj = (w & 3) * 64;

    i32x4 acc[4][4];
    #pragma unroll
    for (int mt = 0; mt < 4; ++mt)
        #pragma unroll
        for (int nt = 0; nt < 4; ++nt) acc[mt][nt] = i32x4{0, 0, 0, 0};

    int ps0 = 1 << 20, ps1 = 1 << 20;        // prev start-row per buffer

    float v0 = 3.0e30f, vnext = 3.0e30f;     // pad -> rows clip to dump
    if (sc) {
        const int ka = k0 + lane;       if (ka  < N_) v0    = coord[ka];
        const int kb2 = k0 + BK + lane; if (kb2 < N_) vnext = coord[kb2];
    }
    __syncthreads();                         // bulk zero complete

    // ---- prologue: scatter window 0 -> buf 0 (pre-zeroed, no clean) ----
    if (sc) {
        const float u  = (v0 - bin0) * invbw;
        const float st = rintf(u) - 3.0f;    // window covers d in [-3.5, 3.5]
        const float d0 = u - st;
        float E = 127.0f * EXP2(-CS2 * d0 * d0);
        float G = EXP2(fmaf(d0 + d0, CS2, -CS2));
        int rr = (int)st - rowlo;
        ps0 = rr;
        const int dmp = cb0 + (int)clip * LDKB;
        #pragma unroll
        for (int j = 0; j < WINB; ++j) {
            tb[((unsigned)rr < clip) ? (cb0 + rr * LDKB) : dmp] =
                (char)(int)(E + 0.5f);
            E *= G; G *= HINV; ++rr;
        }
    }
    __syncthreads();

    for (int ks = 0; ks < KSTEPS; ++ks) {
        const int q = ks & 1;
        // ---- prefetch window ks+2 ----
        float vpre = 3.0e30f;
        if (sc && (ks + 2) < KSTEPS) {
            const int ka = k0 + (ks + 2) * BK + lane;
            if (ka < N_) vpre = coord[ka];
        }
        // ---- scatter window ks+1 into buf q^1 (clean own old cells) ----
        if (sc && (ks + 1) < KSTEPS) {
            const int qn  = q ^ 1;
            const int bqn = qn * BUFB + cb0;
            const int dmp = bqn + (int)clip * LDKB;
            const int ps  = qn ? ps1 : ps0;
            if (ps < (1 << 19)) {
                #pragma unroll
                for (int j = 0; j < WINB; ++j) {
                    const int rr = ps + j;
                    tb[((unsigned)rr < clip) ? (bqn + rr * LDKB) : dmp] = 0;
                }
            }
            const float u  = (vnext - bin0) * invbw;
            const float st = rintf(u) - 3.0f;
            const float d0 = u - st;
            float E = 127.0f * EXP2(-CS2 * d0 * d0);
            float G = EXP2(fmaf(d0 + d0, CS2, -CS2));
            int rr = (int)st - rowlo;
            if (qn) ps1 = rr; else ps0 = rr;
            #pragma unroll
            for (int j = 0; j < WINB; ++j) {
                tb[((unsigned)rr < clip) ? (bqn + rr * LDKB) : dmp] =
                    (char)(int)(E + 0.5f);
                E *= G; G *= HINV; ++rr;
            }
        }
        vnext = vpre;

        // ---- consume buf q: K=64 in one mfma per frag-pair ----
        const char* bufA = tb + q * BUFB;          // kx tile (128 rows)
        const char* bufB = tb + q * BUFB + AXA;    // ky tile (256 rows)
        i32x4 af[4], bfr[4];
        #pragma unroll
        for (int t4 = 0; t4 < 4; ++t4)
            af[t4] = *(const i32x4*)(bufA + (R0 + t4 * 16 + lm) * LDKB + quad * 16);
        #pragma unroll
        for (int t4 = 0; t4 < 4; ++t4)
            bfr[t4] = *(const i32x4*)(bufB + (wj + t4 * 16 + lm) * LDKB + quad * 16);
        #pragma unroll
        for (int mt = 0; mt < 4; ++mt)
            #pragma unroll
            for (int nt = 0; nt < 4; ++nt)
                acc[mt][nt] = __builtin_amdgcn_mfma_i32_16x16x64_i8(
                    af[mt], bfr[nt], acc[mt][nt], 0, 0, 0);
        __syncthreads();                     // the only barrier per step
    }

    // ---- epilogue: bf16 split-K partial (C/D: col=lane&15, row=quad*4+e) ----
    float tsum = 0.f;
    {
        unsigned short* pb = partial + (((size_t)chunk * B_ + b) << 16);
        #pragma unroll
        for (int mt = 0; mt < 4; ++mt) {
            const int row0 = ilo + R0 + mt * 16 + quad * 4;
            #pragma unroll
            for (int nt = 0; nt < 4; ++nt) {
                const int col = wj + nt * 16 + lm;
                const i32x4 a = acc[mt][nt];
                #pragma unroll
                for (int e = 0; e < 4; ++e) {
                    const float v = (float)a[e];
                    pb[(size_t)(row0 + e) * M_ + col] = bf16ru(v);
                    tsum += v;
                }
            }
        }
    }

    // ---- block sum -> ws2 ----
    #pragma unroll
    for (int off = 32; off; off >>= 1) tsum += __shfl_xor(tsum, off);
    if (lane == 0) sred[w] = tsum;
    __syncthreads();
    if (tid == 0) {
        float bsum = 0.f;
        #pragma unroll
        for (int i = 0; i < 8; ++i) bsum += sred[i];
        if (wide) {
            const int bid = (b * NCH + chunk) * 2 + itile;  // in [b*128, +128)
            ws2[bid] = bsum;
        } else {
            atomicAdd(&ws2[b], bsum);
        }
    }
}

__global__ __launch_bounds__(256) void kde_tail(
    const unsigned short* __restrict__ partial, const float* __restrict__ ws2,
    float* __restrict__ out, int wide)
{
    __shared__ float sred[4];
    __shared__ float snorm;
    const int tid = threadIdx.x;
    const int cellIdx = blockIdx.x * 256 + tid;     // float4 index, 16384/batch
    const int bb = cellIdx >> 14;                   // uniform per block
    const int cb = cellIdx & 16383;

    float nrm;
    if (wide) {
        float t = (tid < 128) ? ws2[bb * 128 + tid] : 0.f;
        #pragma unroll
        for (int off = 32; off; off >>= 1) t += __shfl_xor(t, off);
        if ((tid & 63) == 0) sred[tid >> 6] = t;
        __syncthreads();
        if (tid == 0) snorm = sred[0] + sred[1] + sred[2] + sred[3];
        __syncthreads();
        nrm = snorm;
    } else {
        nrm = ws2[bb];
    }

    float4 a = {0.f, 0.f, 0.f, 0.f};
    #pragma unroll 4
    for (int c = 0; c < NCH; ++c) {
        const ushort4 v = *(const ushort4*)(partial +
            (((size_t)c * B_ + bb) << 16) + (size_t)cb * 4);
        a.x += bf2f(v.x); a.y += bf2f(v.y); a.z += bf2f(v.z); a.w += bf2f(v.w);
    }
    // i8 scale (127^2) cancels: both partials and nrm carry it.
    const float sc = 1.0f / (nrm + 1e-10f);
    a.x *= sc; a.y *= sc; a.z *= sc; a.w *= sc;
    ((float4*)out)[cellIdx] = a;
}

extern "C" void kernel_launch(void* const* d_in, const int* in_sizes, int n_in,
                              void* d_out, int out_size, void* d_ws, size_t ws_size,
                              hipStream_t stream)
{
    const float* xs   = (const float*)d_in[0];
    const float* ys   = (const float*)d_in[1];
    const float* bins = (const float*)d_in[2];
    float* out = (float*)d_out;
    unsigned short* partial = (unsigned short*)d_ws;        // 32 MB bf16
    const size_t PSZ = (size_t)NCH * B_ * M_ * M_ * sizeof(unsigned short);
    float* ws2 = (float*)((char*)d_ws + PSZ);

    const int wide = (ws_size >= PSZ + 4096) ? 1 : 0;
    if (!wide) hipMemsetAsync(ws2, 0, 4 * sizeof(float), stream);

    kde_gemm<<<dim3(2, NCH, B_), dim3(BLOCK), 0, stream>>>(
        xs, ys, bins, partial, ws2, wide);
    kde_tail<<<dim3(B_ * M_ * M_ / (4 * 256)), dim3(256), 0, stream>>>(
        partial, ws2, out, wide);
}

// Round 13
// 89.141 us; speedup vs baseline: 1.0275x; 1.0275x over previous
//
#include <hip/hip_runtime.h>

// KDE joint histogram = dense split-K INT8 MFMA GEMM, sparse scatter staging,
// ping-pong K-tiles (1 barrier/step), asymmetric wave tiles.
// joint[b,i,j] = sum_k kx[b,k,i]*ky[b,k,j]; quantize q = round(127*kernel)
// (i8 zeroes below 1/254 -> inherent ±3.33-bin support, window = 7 bins).
// The 127^2 scale cancels in normalization; i32 accumulation is exact.
// mfma_i32_16x16x64_i8: K=64 per instr, b128 frag = 16 i8 -> DS read bytes
// and MFMA count both HALVE vs bf16. Any consistent k-permutation in LDS is
// valid (MFMA pairs A/B k-slots identically). bf16 split-K partials -> tail.
// R12 lesson: widening the tile to 128x256 (halving scatter/barriers per
// output) REGRESSED — the kernel is not staging-bound; this R11 config
// (3 blocks/CU, 4-wave barriers) is the measured optimum (89.8 us total,
// of which ~47 us is the harness's immovable 268 MB d_ws re-poison fill).

#define B_     4
#define N_     50000
#define M_     256
#define BK     64
#define NCH    48               // grid 4*48*4 = 768 = 3 blocks/CU (LDS 41.3KB)
#define KSTEPS 17               // 17*64 = 1088/chunk; 48*1088 = 52224 >= N
#define KCH    (KSTEPS * BK)
#define LDKB   80               // tile row stride in BYTES (16B-aligned)
#define ROWS   129              // 128 + dump row for clipped writes
#define AXB    (ROWS * LDKB)    // bytes per axis tile (10320)
#define BUFB   (2 * AXB)        // bytes per ping-pong buffer (20640)
#define BLOCK  256
#define WINB   7                // bins per window (covers ±3.5)
#define CS2    0.72134752f      // 0.5*log2(e): exp(-0.5 d^2) = 2^(-CS2*d^2)
#define HINV   0.36787944f      // 2^(-2*CS2) = 1/e

#if __has_builtin(__builtin_amdgcn_exp2f)
  #define EXP2(t) __builtin_amdgcn_exp2f(t)
#else
  #define EXP2(t) exp2f(t)
#endif

typedef __attribute__((ext_vector_type(4))) int i32x4;

__device__ __forceinline__ unsigned short bf16ru(float f) {  // round-half-up
    return (unsigned short)((__builtin_bit_cast(unsigned, f) + 0x8000u) >> 16);
}
__device__ __forceinline__ float bf2f(unsigned short u) {
    return __builtin_bit_cast(float, ((unsigned)u) << 16);
}

// One chunk's K-loop + epilogue for a wave with MT row-frags at local row R0.
// SCAT waves additionally own one (particle,axis) scatter column (byte colbase
// within each row). All instantiations execute identical barrier sequences.
template<int MT, int R0, bool SCAT>
__device__ __forceinline__ float chunk_loop(
    char* __restrict__ tb, const float* __restrict__ coord,
    int k0, int rowlo, int colbase, float bin0, float invbw,
    int ilo, int jlo, int wj, int lm, int quad, int tid,
    unsigned short* __restrict__ pb)
{
    i32x4 acc[MT][4];
    #pragma unroll
    for (int mt = 0; mt < MT; ++mt)
        #pragma unroll
        for (int nt = 0; nt < 4; ++nt) acc[mt][nt] = i32x4{0, 0, 0, 0};

    int ps0 = 1 << 20, ps1 = 1 << 20;        // prev start-row per buffer

    float v0 = 3.0e30f, vnext = 3.0e30f;     // pad -> rows clip to dump
    if (SCAT) {
        const int kcol = tid & 63;
        const int ka = k0 + kcol;       if (ka  < N_) v0    = coord[ka];
        const int kb2 = k0 + BK + kcol; if (kb2 < N_) vnext = coord[kb2];
    }
    __syncthreads();                         // bulk zero complete

    // ---- prologue: scatter window 0 -> buf 0 (pre-zeroed, no clean) ----
    if (SCAT) {
        const float u  = (v0 - bin0) * invbw;
        const float st = rintf(u) - 3.0f;    // window covers d in [-3.5, 3.5]
        const float d0 = u - st;             // in [2.5, 3.5]
        float E = 127.0f * EXP2(-CS2 * d0 * d0);
        float G = EXP2(fmaf(d0 + d0, CS2, -CS2));
        int rr = (int)st - rowlo;
        ps0 = rr;
        const int dmp = colbase + 128 * LDKB;
        #pragma unroll
        for (int j = 0; j < WINB; ++j) {
            tb[((unsigned)rr < 128u) ? (colbase + rr * LDKB) : dmp] =
                (char)(int)(E + 0.5f);
            E *= G; G *= HINV; ++rr;
        }
    }
    __syncthreads();

    for (int ks = 0; ks < KSTEPS; ++ks) {
        const int q = ks & 1;
        // ---- prefetch window ks+2 ----
        float vpre = 3.0e30f;
        if (SCAT && (ks + 2) < KSTEPS) {
            const int ka = k0 + (ks + 2) * BK + (tid & 63);
            if (ka < N_) vpre = coord[ka];
        }
        // ---- scatter window ks+1 into buf q^1 (clean own old cells) ----
        if (SCAT && (ks + 1) < KSTEPS) {
            const int qn  = q ^ 1;
            const int bqn = qn * BUFB + colbase;
            const int dmp = bqn + 128 * LDKB;
            const int ps  = qn ? ps1 : ps0;
            if (ps < (1 << 19)) {
                #pragma unroll
                for (int j = 0; j < WINB; ++j) {
                    const int rr = ps + j;
                    tb[((unsigned)rr < 128u) ? (bqn + rr * LDKB) : dmp] = 0;
                }
            }
            const float u  = (vnext - bin0) * invbw;
            const float st = rintf(u) - 3.0f;
            const float d0 = u - st;
            float E = 127.0f * EXP2(-CS2 * d0 * d0);
            float G = EXP2(fmaf(d0 + d0, CS2, -CS2));
            int rr = (int)st - rowlo;
            if (qn) ps1 = rr; else ps0 = rr;
            #pragma unroll
            for (int j = 0; j < WINB; ++j) {
                tb[((unsigned)rr < 128u) ? (bqn + rr * LDKB) : dmp] =
                    (char)(int)(E + 0.5f);
                E *= G; G *= HINV; ++rr;
            }
        }
        vnext = vpre;

        // ---- consume buf q: K=64 in ONE mfma per frag-pair ----
        const char* bufA = tb + q * BUFB;          // axis 0 (kx)
        const char* bufB = tb + q * BUFB + AXB;    // axis 1 (ky)
        i32x4 af[MT], bfr[4];
        #pragma unroll
        for (int t4 = 0; t4 < MT; ++t4)
            af[t4] = *(const i32x4*)(bufA + (R0 + t4 * 16 + lm) * LDKB + quad * 16);
        #pragma unroll
        for (int t4 = 0; t4 < 4; ++t4)
            bfr[t4] = *(const i32x4*)(bufB + (wj + t4 * 16 + lm) * LDKB + quad * 16);
        #pragma unroll
        for (int mt = 0; mt < MT; ++mt)
            #pragma unroll
            for (int nt = 0; nt < 4; ++nt)
                acc[mt][nt] = __builtin_amdgcn_mfma_i32_16x16x64_i8(
                    af[mt], bfr[nt], acc[mt][nt], 0, 0, 0);
        __syncthreads();                     // the only barrier per step
    }

    // ---- epilogue: bf16 split-K partial (C/D: col=lane&15, row=quad*4+e) ----
    float tsum = 0.f;
    #pragma unroll
    for (int mt = 0; mt < MT; ++mt) {
        const int row0 = ilo + R0 + mt * 16 + quad * 4;
        #pragma unroll
        for (int nt = 0; nt < 4; ++nt) {
            const int col = jlo + wj + nt * 16 + lm;
            const i32x4 a = acc[mt][nt];
            #pragma unroll
            for (int e = 0; e < 4; ++e) {
                const float v = (float)a[e];
                pb[(size_t)(row0 + e) * M_ + col] = bf16ru(v);
                tsum += v;
            }
        }
    }
    return tsum;
}

__global__ __launch_bounds__(BLOCK) void kde_gemm(
    const float* __restrict__ xs, const float* __restrict__ ys,
    const float* __restrict__ bins, unsigned short* __restrict__ partial,
    float* __restrict__ ws2, int wide)
{
    __shared__ __align__(16) char tiles[2][2][ROWS][LDKB];  // 41280 B
    __shared__ float sred[4];

    const int tid   = threadIdx.x;
    const int tile  = blockIdx.x;            // 0..3 -> 2x2 tiles of 128
    const int chunk = blockIdx.y;            // 0..NCH-1
    const int b     = blockIdx.z;

    const int ilo = (tile & 1) * 128;
    const int jlo = (tile >> 1) * 128;
    const float bin0  = bins[0];
    const float invbw = 1.0f / (bins[1] - bin0);

    // ---- bulk-zero both buffers (incl. dump rows) ----
    {
        int4* za = (int4*)&tiles[0][0][0][0];
        const int4 z4 = {0, 0, 0, 0};
        for (int t = tid; t < (int)(sizeof(tiles) / 16); t += BLOCK) za[t] = z4;
    }

    // scatter column params (meaningful for tid < 128)
    const int  axis    = (tid >> 6) & 1;     // 0 -> kx tile, 1 -> ky tile
    const int  rowlo   = axis ? jlo : ilo;
    const int  colbase = axis * AXB + (tid & 63);
    const float* coord = (axis ? ys : xs) + b * N_;
    const int  k0 = chunk * KCH;
    char* const tb = &tiles[0][0][0][0];

    // MFMA role
    const int w    = tid >> 6;
    const int wj   = (w & 1) * 64;
    const int lane = tid & 63;
    const int lm   = lane & 15;
    const int quad = lane >> 4;
    unsigned short* pb = partial + (((size_t)chunk * B_ + b) << 16);

    float tsum;
    if (w < 2)   // waves 0-1: scatter + rows [0,48)
        tsum = chunk_loop<3, 0, true >(tb, coord, k0, rowlo, colbase, bin0, invbw,
                                       ilo, jlo, wj, lm, quad, tid, pb);
    else         // waves 2-3: rows [48,128)
        tsum = chunk_loop<5, 48, false>(tb, coord, k0, rowlo, colbase, bin0, invbw,
                                       ilo, jlo, wj, lm, quad, tid, pb);

    // ---- block sum -> ws2 ----
    #pragma unroll
    for (int off = 32; off; off >>= 1) tsum += __shfl_xor(tsum, off);
    if (lane == 0) sred[w] = tsum;
    __syncthreads();
    if (tid == 0) {
        const float bsum = sred[0] + sred[1] + sred[2] + sred[3];
        if (wide) {
            const int bid = (b * NCH + chunk) * 4 + tile;  // in [b*192, +192)
            ws2[bid] = bsum;
        } else {
            atomicAdd(&ws2[b], bsum);
        }
    }
}

__global__ __launch_bounds__(BLOCK) void kde_tail(
    const unsigned short* __restrict__ partial, const float* __restrict__ ws2,
    float* __restrict__ out, int wide)
{
    __shared__ float sred[4];
    __shared__ float snorm;
    const int tid = threadIdx.x;
    const int cellIdx = blockIdx.x * BLOCK + tid;   // float4 index, 16384/batch
    const int bb = cellIdx >> 14;                   // uniform per block
    const int cb = cellIdx & 16383;

    float nrm;
    if (wide) {
        float t = (tid < 4 * NCH) ? ws2[bb * 4 * NCH + tid] : 0.f;
        #pragma unroll
        for (int off = 32; off; off >>= 1) t += __shfl_xor(t, off);
        if ((tid & 63) == 0) sred[tid >> 6] = t;
        __syncthreads();
        if (tid == 0) snorm = sred[0] + sred[1] + sred[2] + sred[3];
        __syncthreads();
        nrm = snorm;
    } else {
        nrm = ws2[bb];
    }

    float4 a = {0.f, 0.f, 0.f, 0.f};
    #pragma unroll 4
    for (int c = 0; c < NCH; ++c) {
        const ushort4 v = *(const ushort4*)(partial +
            (((size_t)c * B_ + bb) << 16) + (size_t)cb * 4);
        a.x += bf2f(v.x); a.y += bf2f(v.y); a.z += bf2f(v.z); a.w += bf2f(v.w);
    }
    // i8 scale (127^2) cancels: both partials and nrm carry it.
    const float sc = 1.0f / (nrm + 1e-10f);
    a.x *= sc; a.y *= sc; a.z *= sc; a.w *= sc;
    ((float4*)out)[cellIdx] = a;
}

extern "C" void kernel_launch(void* const* d_in, const int* in_sizes, int n_in,
                              void* d_out, int out_size, void* d_ws, size_t ws_size,
                              hipStream_t stream)
{
    const float* xs   = (const float*)d_in[0];
    const float* ys   = (const float*)d_in[1];
    const float* bins = (const float*)d_in[2];
    float* out = (float*)d_out;
    unsigned short* partial = (unsigned short*)d_ws;        // 24 MB bf16
    const size_t PSZ = (size_t)NCH * B_ * M_ * M_ * sizeof(unsigned short);
    float* ws2 = (float*)((char*)d_ws + PSZ);

    const int wide = (ws_size >= PSZ + 4096) ? 1 : 0;
    if (!wide) hipMemsetAsync(ws2, 0, 4 * sizeof(float), stream);

    kde_gemm<<<dim3(4, NCH, B_), dim3(BLOCK), 0, stream>>>(
        xs, ys, bins, partial, ws2, wide);
    kde_tail<<<dim3(B_ * M_ * M_ / (4 * BLOCK)), dim3(BLOCK), 0, stream>>>(
        partial, ws2, out, wide);
}